// Round 11
// baseline (115.651 us; speedup 1.0000x reference)
//
#include <hip/hip_runtime.h>

// hnode_prompt_layer_feature_cat_edge
// out[d, 0:128]   = (sum_{e: dst[e]=d} emb[src[e]]) * w
// out[d, 128:160] =  sum_{e: dst[e]=d} e_feat[e]
//
// R11 = R9 (best: 100.9us) with a deeper-MLP gather body:
//  - VGPR cliff is at 64 (m69: waves/CU halve at vgpr=64/128/256), so the
//    28-VGPR R9 body was leaving MLP budget unused. New ft loop issues 8
//    emb-row float4 loads per masked 16-edge superblock (2x R9's depth).
//  - e_feat handled in its own masked loop (full-wave 8 subgroups) so its
//    registers don't extend the ft payload's live range.
//  - masks/clamps follow R9's proven-safe pattern: group-uniform loop entry,
//    shfl sources clamped to [0,cnt-1] (always valid, active lanes),
//    fma-mask zeroes redundant contributions; loops skip when cnt==0 so
//    stale bucket data is never consumed.
//  - scheduling: 1 node per wave, block churn (self-balances; persistent
//    waves regressed in R10). place/memset/ovf identical to R9.

#define D_FT 128
#define D_E 32
#define D_OUT (D_FT + D_E)
#define CAP 32

typedef float f32x4 __attribute__((ext_vector_type(4)));
typedef int   i32x2 __attribute__((ext_vector_type(2)));

__global__ void place_bucket_kernel(const int* __restrict__ src_idx,
                                    const int* __restrict__ dst_idx,
                                    int* __restrict__ cursor,
                                    i32x2* __restrict__ bucket,
                                    int* __restrict__ ovf,
                                    int* __restrict__ ovf_cnt, int E) {
    int i = blockIdx.x * blockDim.x + threadIdx.x;
    if (i >= E) return;
    int d = dst_idx[i];
    int slot = atomicAdd(&cursor[d], 1);
    if (slot < CAP) {
        i32x2 pr; pr.x = src_idx[i]; pr.y = i;
        bucket[(size_t)d * CAP + slot] = pr;
    } else {
        int p = atomicAdd(ovf_cnt, 1);
        ovf[p] = i;
    }
}

__global__ __launch_bounds__(256, 8)
void gather_bucket_kernel(const float* __restrict__ emb,
                          const float* __restrict__ e_feat,
                          const float* __restrict__ w,
                          const int* __restrict__ cursor,
                          const i32x2* __restrict__ bucket,
                          float* __restrict__ out, int N) {
    int g = (blockIdx.x * blockDim.x + threadIdx.x) >> 6;   // node = one wave
    if (g >= N) return;                                     // wave-uniform exit
    const int lane = threadIdx.x & 63;
    const int half = lane >> 5;      // 0/1: which 8-edge slice of the 16/iter
    const int q    = lane & 31;      // float4 slot within the 128-wide row
    const int sub  = lane >> 3;      // e_feat edge-subgroup 0..7 (full wave)
    const int ql8  = lane & 7;       // float4 slot within e_feat row

    // cursor load and bucket load issue INDEPENDENTLY (no guard on bucket).
    // Slots >= cnt hold stale data but are never consumed: loops skip when
    // cnt==0 and all shfl sources are clamped to [0, cnt-1].
    i32x2 pr = __builtin_nontemporal_load(&bucket[(size_t)g * CAP + (lane & 31)]);
    int cnt = cursor[g];
    cnt = cnt > CAP ? CAP : cnt;
    const int c1 = cnt - 1;

    float4 accft = make_float4(0.f, 0.f, 0.f, 0.f);

    // ---- ft: masked 16-edge superblocks, 8 emb rows in flight ----
    for (int i = 0; i < cnt; i += 16) {
        int b  = i + (half << 3);
        int t0 = b + 0, t1 = b + 1, t2 = b + 2, t3 = b + 3;
        int t4 = b + 4, t5 = b + 5, t6 = b + 6, t7 = b + 7;
        int s0 = __shfl(pr.x, t0 < c1 ? t0 : c1, 64);
        int s1 = __shfl(pr.x, t1 < c1 ? t1 : c1, 64);
        int s2 = __shfl(pr.x, t2 < c1 ? t2 : c1, 64);
        int s3 = __shfl(pr.x, t3 < c1 ? t3 : c1, 64);
        int s4 = __shfl(pr.x, t4 < c1 ? t4 : c1, 64);
        int s5 = __shfl(pr.x, t5 < c1 ? t5 : c1, 64);
        int s6 = __shfl(pr.x, t6 < c1 ? t6 : c1, 64);
        int s7 = __shfl(pr.x, t7 < c1 ? t7 : c1, 64);
        float4 v0 = *reinterpret_cast<const float4*>(emb + (size_t)s0 * D_FT + q * 4);
        float4 v1 = *reinterpret_cast<const float4*>(emb + (size_t)s1 * D_FT + q * 4);
        float4 v2 = *reinterpret_cast<const float4*>(emb + (size_t)s2 * D_FT + q * 4);
        float4 v3 = *reinterpret_cast<const float4*>(emb + (size_t)s3 * D_FT + q * 4);
        float4 v4 = *reinterpret_cast<const float4*>(emb + (size_t)s4 * D_FT + q * 4);
        float4 v5 = *reinterpret_cast<const float4*>(emb + (size_t)s5 * D_FT + q * 4);
        float4 v6 = *reinterpret_cast<const float4*>(emb + (size_t)s6 * D_FT + q * 4);
        float4 v7 = *reinterpret_cast<const float4*>(emb + (size_t)s7 * D_FT + q * 4);
        float m0 = (t0 < cnt) ? 1.f : 0.f;
        float m1 = (t1 < cnt) ? 1.f : 0.f;
        float m2 = (t2 < cnt) ? 1.f : 0.f;
        float m3 = (t3 < cnt) ? 1.f : 0.f;
        float m4 = (t4 < cnt) ? 1.f : 0.f;
        float m5 = (t5 < cnt) ? 1.f : 0.f;
        float m6 = (t6 < cnt) ? 1.f : 0.f;
        float m7 = (t7 < cnt) ? 1.f : 0.f;
        accft.x = fmaf(v0.x, m0, accft.x); accft.y = fmaf(v0.y, m0, accft.y);
        accft.z = fmaf(v0.z, m0, accft.z); accft.w = fmaf(v0.w, m0, accft.w);
        accft.x = fmaf(v1.x, m1, accft.x); accft.y = fmaf(v1.y, m1, accft.y);
        accft.z = fmaf(v1.z, m1, accft.z); accft.w = fmaf(v1.w, m1, accft.w);
        accft.x = fmaf(v2.x, m2, accft.x); accft.y = fmaf(v2.y, m2, accft.y);
        accft.z = fmaf(v2.z, m2, accft.z); accft.w = fmaf(v2.w, m2, accft.w);
        accft.x = fmaf(v3.x, m3, accft.x); accft.y = fmaf(v3.y, m3, accft.y);
        accft.z = fmaf(v3.z, m3, accft.z); accft.w = fmaf(v3.w, m3, accft.w);
        accft.x = fmaf(v4.x, m4, accft.x); accft.y = fmaf(v4.y, m4, accft.y);
        accft.z = fmaf(v4.z, m4, accft.z); accft.w = fmaf(v4.w, m4, accft.w);
        accft.x = fmaf(v5.x, m5, accft.x); accft.y = fmaf(v5.y, m5, accft.y);
        accft.z = fmaf(v5.z, m5, accft.z); accft.w = fmaf(v5.w, m5, accft.w);
        accft.x = fmaf(v6.x, m6, accft.x); accft.y = fmaf(v6.y, m6, accft.y);
        accft.z = fmaf(v6.z, m6, accft.z); accft.w = fmaf(v6.w, m6, accft.w);
        accft.x = fmaf(v7.x, m7, accft.x); accft.y = fmaf(v7.y, m7, accft.y);
        accft.z = fmaf(v7.z, m7, accft.z); accft.w = fmaf(v7.w, m7, accft.w);
    }

    // ---- e_feat: masked 8-edge blocks, full-wave 8 subgroups ----
    float4 acce = make_float4(0.f, 0.f, 0.f, 0.f);
    for (int i = 0; i < cnt; i += 8) {
        int te = i + sub;
        int ee = __shfl(pr.y, te < c1 ? te : c1, 64);
        f32x4 a = __builtin_nontemporal_load(
            reinterpret_cast<const f32x4*>(e_feat + (size_t)ee * D_E + ql8 * 4));
        float me = (te < cnt) ? 1.f : 0.f;
        acce.x = fmaf(a.x, me, acce.x); acce.y = fmaf(a.y, me, acce.y);
        acce.z = fmaf(a.z, me, acce.z); acce.w = fmaf(a.w, me, acce.w);
    }

    // combine the two halves' ft partials
    accft.x += __shfl_xor(accft.x, 32, 64);
    accft.y += __shfl_xor(accft.y, 32, 64);
    accft.z += __shfl_xor(accft.z, 32, 64);
    accft.w += __shfl_xor(accft.w, 32, 64);
    // combine e partials across the 8 subgroups (lane bits 3,4,5)
    acce.x += __shfl_xor(acce.x, 8, 64);
    acce.y += __shfl_xor(acce.y, 8, 64);
    acce.z += __shfl_xor(acce.z, 8, 64);
    acce.w += __shfl_xor(acce.w, 8, 64);
    acce.x += __shfl_xor(acce.x, 16, 64);
    acce.y += __shfl_xor(acce.y, 16, 64);
    acce.z += __shfl_xor(acce.z, 16, 64);
    acce.w += __shfl_xor(acce.w, 16, 64);
    acce.x += __shfl_xor(acce.x, 32, 64);
    acce.y += __shfl_xor(acce.y, 32, 64);
    acce.z += __shfl_xor(acce.z, 32, 64);
    acce.w += __shfl_xor(acce.w, 32, 64);

    if (half == 0) {
        float4 wv = *reinterpret_cast<const float4*>(w + q * 4);
        float* o = out + (size_t)g * D_OUT;
        f32x4 r; r.x = accft.x * wv.x; r.y = accft.y * wv.y;
                 r.z = accft.z * wv.z; r.w = accft.w * wv.w;
        __builtin_nontemporal_store(r, reinterpret_cast<f32x4*>(o + q * 4));
        if (q < 8) {
            // lane q (q<8): sub==0, ql8==q -> acce holds float4 slot q total
            f32x4 re; re.x = acce.x; re.y = acce.y; re.z = acce.z; re.w = acce.w;
            __builtin_nontemporal_store(re, reinterpret_cast<f32x4*>(o + D_FT + q * 4));
        }
    }
}

// Drain overflow edges (deg > CAP; ~never fires for this data, correct always).
__global__ void ovf_scatter_kernel(const float* __restrict__ emb,
                                   const float* __restrict__ e_feat,
                                   const float* __restrict__ w,
                                   const int* __restrict__ src_idx,
                                   const int* __restrict__ dst_idx,
                                   const int* __restrict__ ovf,
                                   const int* __restrict__ ovf_cnt,
                                   float* __restrict__ out) {
    int n = *ovf_cnt;
    int total = n * 40;   // 32 ft float4-slots + 8 e float4-slots per edge
    for (int t = blockIdx.x * blockDim.x + threadIdx.x; t < total;
         t += gridDim.x * blockDim.x) {
        int e = t / 40, slot = t % 40;
        int eid = ovf[e];
        int d = dst_idx[eid];
        float* o = out + (size_t)d * D_OUT;
        if (slot < 32) {
            int s = src_idx[eid];
            float4 v  = *reinterpret_cast<const float4*>(emb + (size_t)s * D_FT + slot * 4);
            float4 wv = *reinterpret_cast<const float4*>(w + slot * 4);
            atomicAdd(o + slot * 4 + 0, v.x * wv.x);
            atomicAdd(o + slot * 4 + 1, v.y * wv.y);
            atomicAdd(o + slot * 4 + 2, v.z * wv.z);
            atomicAdd(o + slot * 4 + 3, v.w * wv.w);
        } else {
            int qq = slot - 32;
            float4 ve = *reinterpret_cast<const float4*>(e_feat + (size_t)eid * D_E + qq * 4);
            atomicAdd(o + D_FT + qq * 4 + 0, ve.x);
            atomicAdd(o + D_FT + qq * 4 + 1, ve.y);
            atomicAdd(o + D_FT + qq * 4 + 2, ve.z);
            atomicAdd(o + D_FT + qq * 4 + 3, ve.w);
        }
    }
}

// ---- fallback (R1 atomic path) if ws too small ----
__global__ void scatter_ft_kernel(const float* __restrict__ emb, const float* __restrict__ w,
                                  const int* __restrict__ src_idx, const int* __restrict__ dst_idx,
                                  float* __restrict__ out, int n_items) {
    int idx = blockIdx.x * blockDim.x + threadIdx.x;
    if (idx >= n_items) return;
    int e = idx >> 5, q = idx & 31;
    int s = src_idx[e], d = dst_idx[e];
    const float4 v  = *reinterpret_cast<const float4*>(emb + (size_t)s * D_FT + q * 4);
    const float4 wv = *reinterpret_cast<const float4*>(w + q * 4);
    float* o = out + (size_t)d * D_OUT + q * 4;
    atomicAdd(o + 0, v.x * wv.x); atomicAdd(o + 1, v.y * wv.y);
    atomicAdd(o + 2, v.z * wv.z); atomicAdd(o + 3, v.w * wv.w);
}
__global__ void scatter_e_kernel(const float* __restrict__ e_feat, const int* __restrict__ dst_idx,
                                 float* __restrict__ out, int n_items) {
    int idx = blockIdx.x * blockDim.x + threadIdx.x;
    if (idx >= n_items) return;
    int e = idx >> 3, q = idx & 7;
    int d = dst_idx[e];
    const float4 v = *reinterpret_cast<const float4*>(e_feat + (size_t)e * D_E + q * 4);
    float* o = out + (size_t)d * D_OUT + D_FT + q * 4;
    atomicAdd(o + 0, v.x); atomicAdd(o + 1, v.y);
    atomicAdd(o + 2, v.z); atomicAdd(o + 3, v.w);
}

extern "C" void kernel_launch(void* const* d_in, const int* in_sizes, int n_in,
                              void* d_out, int out_size, void* d_ws, size_t ws_size,
                              hipStream_t stream) {
    const float* emb    = (const float*)d_in[0];   // [N, 128]
    const float* e_feat = (const float*)d_in[1];   // [E, 32]
    const float* w      = (const float*)d_in[2];   // [1, 128]
    const int*   src    = (const int*)d_in[3];     // [E]
    const int*   dst    = (const int*)d_in[4];     // [E]
    float* out = (float*)d_out;                    // [N, 160]

    const int E = in_sizes[3];
    const int N = out_size / D_OUT;

    // ws layout: cursor[N] | ovf_cnt[1] | pad[1] | bucket[N*CAP] i32x2 | ovf[E]
    size_t ints_head = (size_t)N + 2;
    size_t need = ints_head * 4 + (size_t)N * CAP * 8 + (size_t)E * 4;

    if (ws_size >= need) {
        int*   cursor  = (int*)d_ws;
        int*   ovf_cnt = cursor + N;
        i32x2* bucket  = (i32x2*)(cursor + ints_head);
        int*   ovf     = (int*)(bucket + (size_t)N * CAP);

        hipMemsetAsync(cursor, 0, ints_head * sizeof(int), stream);
        place_bucket_kernel<<<(E + 255) / 256, 256, 0, stream>>>(
            src, dst, cursor, bucket, ovf, ovf_cnt, E);
        gather_bucket_kernel<<<((size_t)N * 64 + 255) / 256, 256, 0, stream>>>(
            emb, e_feat, w, cursor, bucket, out, N);
        ovf_scatter_kernel<<<128, 256, 0, stream>>>(
            emb, e_feat, w, src, dst, ovf, ovf_cnt, out);
    } else {
        hipMemsetAsync(d_out, 0, (size_t)out_size * sizeof(float), stream);
        int items_ft = E * 32, items_e = E * 8;
        scatter_ft_kernel<<<(items_ft + 255) / 256, 256, 0, stream>>>(emb, w, src, dst, out, items_ft);
        scatter_e_kernel<<<(items_e + 255) / 256, 256, 0, stream>>>(e_feat, dst, out, items_e);
    }
}

// Round 12
// 101.302 us; speedup vs baseline: 1.1416x; 1.1416x over previous
//
#include <hip/hip_runtime.h>

// hnode_prompt_layer_feature_cat_edge
// out[d, 0:128]   = (sum_{e: dst[e]=d} emb[src[e]]) * w
// out[d, 128:160] =  sum_{e: dst[e]=d} e_feat[e]
//
// R12 = R9 (best) with the gather main loop software-pipelined 2-deep:
//  - prologue issues block0's 5 loads (4 emb float4 + 1 e_feat f32x4);
//  - each loop iteration issues block i's loads FIRST, then accumulates
//    block i-8 (compiler emits counted vmcnt: wait on old 5 while new 5
//    are outstanding) -> ~2x in-flight depth, no full-drain stall;
//  - epilogue accumulates the last in-flight block; masked tail unchanged.
//  R11 lesson: never separate e_feat loads into their own loop (in-order
//  issue serializes them behind the ft loop's waitcnts).

#define D_FT 128
#define D_E 32
#define D_OUT (D_FT + D_E)
#define CAP 32

typedef float f32x4 __attribute__((ext_vector_type(4)));
typedef int   i32x2 __attribute__((ext_vector_type(2)));

__global__ void place_bucket_kernel(const int* __restrict__ src_idx,
                                    const int* __restrict__ dst_idx,
                                    int* __restrict__ cursor,
                                    i32x2* __restrict__ bucket,
                                    int* __restrict__ ovf,
                                    int* __restrict__ ovf_cnt, int E) {
    int i = blockIdx.x * blockDim.x + threadIdx.x;
    if (i >= E) return;
    int d = dst_idx[i];
    int slot = atomicAdd(&cursor[d], 1);
    if (slot < CAP) {
        i32x2 pr; pr.x = src_idx[i]; pr.y = i;
        bucket[(size_t)d * CAP + slot] = pr;
    } else {
        int p = atomicAdd(ovf_cnt, 1);
        ovf[p] = i;
    }
}

__global__ void gather_bucket_kernel(const float* __restrict__ emb,
                                     const float* __restrict__ e_feat,
                                     const float* __restrict__ w,
                                     const int* __restrict__ cursor,
                                     const i32x2* __restrict__ bucket,
                                     float* __restrict__ out, int N) {
    int g = (blockIdx.x * blockDim.x + threadIdx.x) >> 6;   // node = one wave
    if (g >= N) return;                                     // wave-uniform exit
    const int lane = threadIdx.x & 63;
    const int half = lane >> 5;      // 0/1: which 4-edge slice of the 8/iter
    const int q    = lane & 31;      // float4 slot within the 128-wide row
    const int qg   = q >> 3;         // e_feat edge-subgroup 0..3 within half
    const int ql   = q & 7;          // float4 slot within e_feat row

    // cursor load and bucket load issue INDEPENDENTLY (no guard on bucket).
    // Slots >= cnt hold stale data but are never consumed as indices without
    // clamping, and clamped-redundant loads only touch valid rows.
    i32x2 pr = __builtin_nontemporal_load(&bucket[(size_t)g * CAP + (lane & 31)]);
    int cnt = cursor[g];
    cnt = cnt > CAP ? CAP : cnt;

    float4 accft = make_float4(0.f, 0.f, 0.f, 0.f);
    float4 acce  = make_float4(0.f, 0.f, 0.f, 0.f);  // partial for (half,qg)

    int i = 0;
    if (cnt >= 8) {
        // ---- prologue: block 0's loads in flight ----
        int b  = (half << 2);
        int s0 = __shfl(pr.x, b + 0, 64);
        int s1 = __shfl(pr.x, b + 1, 64);
        int s2 = __shfl(pr.x, b + 2, 64);
        int s3 = __shfl(pr.x, b + 3, 64);
        int ee = __shfl(pr.y, b + qg, 64);
        float4 v0 = *reinterpret_cast<const float4*>(emb + (size_t)s0 * D_FT + q * 4);
        float4 v1 = *reinterpret_cast<const float4*>(emb + (size_t)s1 * D_FT + q * 4);
        float4 v2 = *reinterpret_cast<const float4*>(emb + (size_t)s2 * D_FT + q * 4);
        float4 v3 = *reinterpret_cast<const float4*>(emb + (size_t)s3 * D_FT + q * 4);
        f32x4 a = __builtin_nontemporal_load(
            reinterpret_cast<const f32x4*>(e_feat + (size_t)ee * D_E + ql * 4));

        for (i = 8; i + 8 <= cnt; i += 8) {
            // ---- issue block i's loads BEFORE consuming block i-8 ----
            int b2  = i + (half << 2);
            int t0 = __shfl(pr.x, b2 + 0, 64);
            int t1 = __shfl(pr.x, b2 + 1, 64);
            int t2 = __shfl(pr.x, b2 + 2, 64);
            int t3 = __shfl(pr.x, b2 + 3, 64);
            int e2 = __shfl(pr.y, b2 + qg, 64);
            float4 u0 = *reinterpret_cast<const float4*>(emb + (size_t)t0 * D_FT + q * 4);
            float4 u1 = *reinterpret_cast<const float4*>(emb + (size_t)t1 * D_FT + q * 4);
            float4 u2 = *reinterpret_cast<const float4*>(emb + (size_t)t2 * D_FT + q * 4);
            float4 u3 = *reinterpret_cast<const float4*>(emb + (size_t)t3 * D_FT + q * 4);
            f32x4 a2 = __builtin_nontemporal_load(
                reinterpret_cast<const f32x4*>(e_feat + (size_t)e2 * D_E + ql * 4));
            // ---- accumulate block i-8 (waits only on the older 5 loads) ----
            accft.x += (v0.x + v1.x) + (v2.x + v3.x);
            accft.y += (v0.y + v1.y) + (v2.y + v3.y);
            accft.z += (v0.z + v1.z) + (v2.z + v3.z);
            accft.w += (v0.w + v1.w) + (v2.w + v3.w);
            acce.x += a.x; acce.y += a.y; acce.z += a.z; acce.w += a.w;
            v0 = u0; v1 = u1; v2 = u2; v3 = u3; a = a2;
        }
        // ---- epilogue: accumulate the last in-flight block ----
        accft.x += (v0.x + v1.x) + (v2.x + v3.x);
        accft.y += (v0.y + v1.y) + (v2.y + v3.y);
        accft.z += (v0.z + v1.z) + (v2.z + v3.z);
        accft.w += (v0.w + v1.w) + (v2.w + v3.w);
        acce.x += a.x; acce.y += a.y; acce.z += a.z; acce.w += a.w;
    }
    // Remainder (cnt - i in [1,7] when taken): ONE masked full-width block.
    // Group-uniform entry; shfl sources clamped to [0, cnt-1] (valid, active
    // lanes); loads use clamped indices (redundant -> same line, L1-hit);
    // fma masks zero the redundant contributions.
    if (i < cnt) {
        const int c1 = cnt - 1;
        int b  = i + (half << 2);
        int t0 = b + 0, t1 = b + 1, t2 = b + 2, t3 = b + 3, te = b + qg;
        int s0 = __shfl(pr.x, t0 < c1 ? t0 : c1, 64);
        int s1 = __shfl(pr.x, t1 < c1 ? t1 : c1, 64);
        int s2 = __shfl(pr.x, t2 < c1 ? t2 : c1, 64);
        int s3 = __shfl(pr.x, t3 < c1 ? t3 : c1, 64);
        int ee = __shfl(pr.y, te < c1 ? te : c1, 64);
        float4 v0 = *reinterpret_cast<const float4*>(emb + (size_t)s0 * D_FT + q * 4);
        float4 v1 = *reinterpret_cast<const float4*>(emb + (size_t)s1 * D_FT + q * 4);
        float4 v2 = *reinterpret_cast<const float4*>(emb + (size_t)s2 * D_FT + q * 4);
        float4 v3 = *reinterpret_cast<const float4*>(emb + (size_t)s3 * D_FT + q * 4);
        f32x4 a = __builtin_nontemporal_load(
            reinterpret_cast<const f32x4*>(e_feat + (size_t)ee * D_E + ql * 4));
        float m0 = (t0 < cnt) ? 1.f : 0.f;
        float m1 = (t1 < cnt) ? 1.f : 0.f;
        float m2 = (t2 < cnt) ? 1.f : 0.f;
        float m3 = (t3 < cnt) ? 1.f : 0.f;
        float me = (te < cnt) ? 1.f : 0.f;
        accft.x = fmaf(v0.x, m0, accft.x); accft.y = fmaf(v0.y, m0, accft.y);
        accft.z = fmaf(v0.z, m0, accft.z); accft.w = fmaf(v0.w, m0, accft.w);
        accft.x = fmaf(v1.x, m1, accft.x); accft.y = fmaf(v1.y, m1, accft.y);
        accft.z = fmaf(v1.z, m1, accft.z); accft.w = fmaf(v1.w, m1, accft.w);
        accft.x = fmaf(v2.x, m2, accft.x); accft.y = fmaf(v2.y, m2, accft.y);
        accft.z = fmaf(v2.z, m2, accft.z); accft.w = fmaf(v2.w, m2, accft.w);
        accft.x = fmaf(v3.x, m3, accft.x); accft.y = fmaf(v3.y, m3, accft.y);
        accft.z = fmaf(v3.z, m3, accft.z); accft.w = fmaf(v3.w, m3, accft.w);
        acce.x = fmaf(a.x, me, acce.x); acce.y = fmaf(a.y, me, acce.y);
        acce.z = fmaf(a.z, me, acce.z); acce.w = fmaf(a.w, me, acce.w);
    }

    // combine the two halves' ft partials
    accft.x += __shfl_xor(accft.x, 32, 64);
    accft.y += __shfl_xor(accft.y, 32, 64);
    accft.z += __shfl_xor(accft.z, 32, 64);
    accft.w += __shfl_xor(accft.w, 32, 64);
    // combine e partials: across qg (8,16) then across halves (32)
    acce.x += __shfl_xor(acce.x, 8, 64);
    acce.y += __shfl_xor(acce.y, 8, 64);
    acce.z += __shfl_xor(acce.z, 8, 64);
    acce.w += __shfl_xor(acce.w, 8, 64);
    acce.x += __shfl_xor(acce.x, 16, 64);
    acce.y += __shfl_xor(acce.y, 16, 64);
    acce.z += __shfl_xor(acce.z, 16, 64);
    acce.w += __shfl_xor(acce.w, 16, 64);
    acce.x += __shfl_xor(acce.x, 32, 64);
    acce.y += __shfl_xor(acce.y, 32, 64);
    acce.z += __shfl_xor(acce.z, 32, 64);
    acce.w += __shfl_xor(acce.w, 32, 64);

    if (half == 0) {
        float4 wv = *reinterpret_cast<const float4*>(w + q * 4);
        float* o = out + (size_t)g * D_OUT;
        f32x4 r; r.x = accft.x * wv.x; r.y = accft.y * wv.y;
                 r.z = accft.z * wv.z; r.w = accft.w * wv.w;
        __builtin_nontemporal_store(r, reinterpret_cast<f32x4*>(o + q * 4));
        if (q < 8) {
            f32x4 re; re.x = acce.x; re.y = acce.y; re.z = acce.z; re.w = acce.w;
            __builtin_nontemporal_store(re, reinterpret_cast<f32x4*>(o + D_FT + q * 4));
        }
    }
}

// Drain overflow edges (deg > CAP; ~never fires for this data, correct always).
__global__ void ovf_scatter_kernel(const float* __restrict__ emb,
                                   const float* __restrict__ e_feat,
                                   const float* __restrict__ w,
                                   const int* __restrict__ src_idx,
                                   const int* __restrict__ dst_idx,
                                   const int* __restrict__ ovf,
                                   const int* __restrict__ ovf_cnt,
                                   float* __restrict__ out) {
    int n = *ovf_cnt;
    int total = n * 40;   // 32 ft float4-slots + 8 e float4-slots per edge
    for (int t = blockIdx.x * blockDim.x + threadIdx.x; t < total;
         t += gridDim.x * blockDim.x) {
        int e = t / 40, slot = t % 40;
        int eid = ovf[e];
        int d = dst_idx[eid];
        float* o = out + (size_t)d * D_OUT;
        if (slot < 32) {
            int s = src_idx[eid];
            float4 v  = *reinterpret_cast<const float4*>(emb + (size_t)s * D_FT + slot * 4);
            float4 wv = *reinterpret_cast<const float4*>(w + slot * 4);
            atomicAdd(o + slot * 4 + 0, v.x * wv.x);
            atomicAdd(o + slot * 4 + 1, v.y * wv.y);
            atomicAdd(o + slot * 4 + 2, v.z * wv.z);
            atomicAdd(o + slot * 4 + 3, v.w * wv.w);
        } else {
            int qq = slot - 32;
            float4 ve = *reinterpret_cast<const float4*>(e_feat + (size_t)eid * D_E + qq * 4);
            atomicAdd(o + D_FT + qq * 4 + 0, ve.x);
            atomicAdd(o + D_FT + qq * 4 + 1, ve.y);
            atomicAdd(o + D_FT + qq * 4 + 2, ve.z);
            atomicAdd(o + D_FT + qq * 4 + 3, ve.w);
        }
    }
}

// ---- fallback (R1 atomic path) if ws too small ----
__global__ void scatter_ft_kernel(const float* __restrict__ emb, const float* __restrict__ w,
                                  const int* __restrict__ src_idx, const int* __restrict__ dst_idx,
                                  float* __restrict__ out, int n_items) {
    int idx = blockIdx.x * blockDim.x + threadIdx.x;
    if (idx >= n_items) return;
    int e = idx >> 5, q = idx & 31;
    int s = src_idx[e], d = dst_idx[e];
    const float4 v  = *reinterpret_cast<const float4*>(emb + (size_t)s * D_FT + q * 4);
    const float4 wv = *reinterpret_cast<const float4*>(w + q * 4);
    float* o = out + (size_t)d * D_OUT + q * 4;
    atomicAdd(o + 0, v.x * wv.x); atomicAdd(o + 1, v.y * wv.y);
    atomicAdd(o + 2, v.z * wv.z); atomicAdd(o + 3, v.w * wv.w);
}
__global__ void scatter_e_kernel(const float* __restrict__ e_feat, const int* __restrict__ dst_idx,
                                 float* __restrict__ out, int n_items) {
    int idx = blockIdx.x * blockDim.x + threadIdx.x;
    if (idx >= n_items) return;
    int e = idx >> 3, q = idx & 7;
    int d = dst_idx[e];
    const float4 v = *reinterpret_cast<const float4*>(e_feat + (size_t)e * D_E + q * 4);
    float* o = out + (size_t)d * D_OUT + D_FT + q * 4;
    atomicAdd(o + 0, v.x); atomicAdd(o + 1, v.y);
    atomicAdd(o + 2, v.z); atomicAdd(o + 3, v.w);
}

extern "C" void kernel_launch(void* const* d_in, const int* in_sizes, int n_in,
                              void* d_out, int out_size, void* d_ws, size_t ws_size,
                              hipStream_t stream) {
    const float* emb    = (const float*)d_in[0];   // [N, 128]
    const float* e_feat = (const float*)d_in[1];   // [E, 32]
    const float* w      = (const float*)d_in[2];   // [1, 128]
    const int*   src    = (const int*)d_in[3];     // [E]
    const int*   dst    = (const int*)d_in[4];     // [E]
    float* out = (float*)d_out;                    // [N, 160]

    const int E = in_sizes[3];
    const int N = out_size / D_OUT;

    // ws layout: cursor[N] | ovf_cnt[1] | pad[1] | bucket[N*CAP] i32x2 | ovf[E]
    size_t ints_head = (size_t)N + 2;
    size_t need = ints_head * 4 + (size_t)N * CAP * 8 + (size_t)E * 4;

    if (ws_size >= need) {
        int*   cursor  = (int*)d_ws;
        int*   ovf_cnt = cursor + N;
        i32x2* bucket  = (i32x2*)(cursor + ints_head);
        int*   ovf     = (int*)(bucket + (size_t)N * CAP);

        hipMemsetAsync(cursor, 0, ints_head * sizeof(int), stream);
        place_bucket_kernel<<<(E + 255) / 256, 256, 0, stream>>>(
            src, dst, cursor, bucket, ovf, ovf_cnt, E);
        gather_bucket_kernel<<<((size_t)N * 64 + 255) / 256, 256, 0, stream>>>(
            emb, e_feat, w, cursor, bucket, out, N);
        ovf_scatter_kernel<<<128, 256, 0, stream>>>(
            emb, e_feat, w, src, dst, ovf, ovf_cnt, out);
    } else {
        hipMemsetAsync(d_out, 0, (size_t)out_size * sizeof(float), stream);
        int items_ft = E * 32, items_e = E * 8;
        scatter_ft_kernel<<<(items_ft + 255) / 256, 256, 0, stream>>>(emb, w, src, dst, out, items_ft);
        scatter_e_kernel<<<(items_e + 255) / 256, 256, 0, stream>>>(e_feat, dst, out, items_e);
    }
}